// Round 4
// baseline (79.534 us; speedup 1.0000x reference)
//
#include <hip/hip_runtime.h>

// One wavefront = TWO 9-qubit patch circuits, interleaved for ILP.
// (Round-3 post-mortem: kernel is latency-bound — serial gate chain per wave,
//  VALUBusy ~38%. Two independent states per wave doubles issueable work.)
//
// Qubit -> bit remap (all post-ring gates register-local):
//   qubit 0 -> reg bit 0   qubit 3 -> reg bit 1   qubit 6 -> reg bit 2
//   qubit 1 -> lane bit 0  qubit 2 -> lane bit 1  qubit 4 -> lane bit 2
//   qubit 5 -> lane bit 3  qubit 7 -> lane bit 4  qubit 8 -> lane bit 5
//
// Algebraic folds:
//   enc RY(a_q) + conv1 RY(w_q) on |0> == RY(a_q+w_q)|0>  -> real product state
//   all 9 conv1 RZ == one diagonal phase; its lane part + per-r phase factors
//   are patch-independent -> computed once, shared by both patches.
//
// Epilogue: per-wave (ex,ey,ez)x2 -> feats in d_ws; FC in a second kernel.
// (Round-2 lesson: fused atomicAdd onto 80 floats serialized at the coherence
//  point — never again. Harness's 256MB d_ws poison-fill (~40us) is a fixed
//  floor regardless of d_ws use.)

__device__ __forceinline__ float shx(float v, int m) { return __shfl_xor(v, m, 64); }
__device__ __forceinline__ float fsel(int c, float a, float b) { return c ? a : b; }

// ---- dual-patch gates: A and B interleaved ----

template <int TM> __device__ __forceinline__
void ry2(float (&reA)[8], float (&imA)[8], float (&reB)[8], float (&imB)[8],
         float c, float s) {
#pragma unroll
  for (int r0 = 0; r0 < 8; ++r0) if (!(r0 & TM)) {
    const int r1 = r0 | TM;
    { float a = reA[r0], b = reA[r1]; reA[r0] = c*a - s*b; reA[r1] = s*a + c*b; }
    { float a = reB[r0], b = reB[r1]; reB[r0] = c*a - s*b; reB[r1] = s*a + c*b; }
    { float a = imA[r0], b = imA[r1]; imA[r0] = c*a - s*b; imA[r1] = s*a + c*b; }
    { float a = imB[r0], b = imB[r1]; imB[r0] = c*a - s*b; imB[r1] = s*a + c*b; }
  }
}

template <int TM> __device__ __forceinline__
void rz2(float (&reA)[8], float (&imA)[8], float (&reB)[8], float (&imB)[8],
         float c, float s) {
#pragma unroll
  for (int r = 0; r < 8; ++r) {
    const float sg = (r & TM) ? s : -s;
    { float a = reA[r], b = imA[r]; reA[r] = c*a - sg*b; imA[r] = c*b + sg*a; }
    { float a = reB[r], b = imB[r]; reB[r] = c*a - sg*b; imB[r] = c*b + sg*a; }
  }
}

template <int CM, int TM> __device__ __forceinline__
void cx_rr2(float (&reA)[8], float (&imA)[8], float (&reB)[8], float (&imB)[8]) {
#pragma unroll
  for (int r0 = 0; r0 < 8; ++r0) if ((r0 & CM) && !(r0 & TM)) {
    const int r1 = r0 | TM;
    { float t = reA[r0]; reA[r0] = reA[r1]; reA[r1] = t; }
    { float t = imA[r0]; imA[r0] = imA[r1]; imA[r1] = t; }
    { float t = reB[r0]; reB[r0] = reB[r1]; reB[r1] = t; }
    { float t = imB[r0]; imB[r0] = imB[r1]; imB[r1] = t; }
  }
}

template <int CL, int TM> __device__ __forceinline__
void cx_lr2(float (&reA)[8], float (&imA)[8], float (&reB)[8], float (&imB)[8], int lane) {
  const bool ctl = (lane & CL) != 0;
#pragma unroll
  for (int r0 = 0; r0 < 8; ++r0) if (!(r0 & TM)) {
    const int r1 = r0 | TM;
    { float a0 = reA[r0], a1 = reA[r1];
      reA[r0] = ctl ? a1 : a0; reA[r1] = ctl ? a0 : a1; }
    { float a0 = imA[r0], a1 = imA[r1];
      imA[r0] = ctl ? a1 : a0; imA[r1] = ctl ? a0 : a1; }
    { float a0 = reB[r0], a1 = reB[r1];
      reB[r0] = ctl ? a1 : a0; reB[r1] = ctl ? a0 : a1; }
    { float a0 = imB[r0], a1 = imB[r1];
      imB[r0] = ctl ? a1 : a0; imB[r1] = ctl ? a0 : a1; }
  }
}

template <int CM, int TL> __device__ __forceinline__
void cx_rl2(float (&reA)[8], float (&imA)[8], float (&reB)[8], float (&imB)[8]) {
#pragma unroll
  for (int r = 0; r < 8; ++r) if (r & CM) {
    reA[r] = shx(reA[r], TL);
    reB[r] = shx(reB[r], TL);
    imA[r] = shx(imA[r], TL);
    imB[r] = shx(imB[r], TL);
  }
}

template <int CL, int TL> __device__ __forceinline__
void cx_ll2(float (&reA)[8], float (&imA)[8], float (&reB)[8], float (&imB)[8], int lane) {
  const bool ctl = (lane & CL) != 0;
#pragma unroll
  for (int r = 0; r < 8; ++r) {
    const float orA = shx(reA[r], TL), oiA = shx(imA[r], TL);
    const float orB = shx(reB[r], TL), oiB = shx(imB[r], TL);
    reA[r] = ctl ? orA : reA[r]; imA[r] = ctl ? oiA : imA[r];
    reB[r] = ctl ? orB : reB[r]; imB[r] = ctl ? oiB : imB[r];
  }
}

template <int CL, int TM> __device__ __forceinline__
void crx_lr2(float (&reA)[8], float (&imA)[8], float (&reB)[8], float (&imB)[8],
             int lane, float co, float si) {
  const bool ctl = (lane & CL) != 0;
#pragma unroll
  for (int r0 = 0; r0 < 8; ++r0) if (!(r0 & TM)) {
    const int r1 = r0 | TM;
    { const float r0r = reA[r0], r0i = imA[r0], r1r = reA[r1], r1i = imA[r1];
      const float n0r = co*r0r + si*r1i, n0i = co*r0i - si*r1r;
      const float n1r = co*r1r + si*r0i, n1i = co*r1i - si*r0r;
      reA[r0] = ctl ? n0r : r0r; imA[r0] = ctl ? n0i : r0i;
      reA[r1] = ctl ? n1r : r1r; imA[r1] = ctl ? n1i : r1i; }
    { const float r0r = reB[r0], r0i = imB[r0], r1r = reB[r1], r1i = imB[r1];
      const float n0r = co*r0r + si*r1i, n0i = co*r0i - si*r1r;
      const float n1r = co*r1r + si*r0i, n1i = co*r1i - si*r0r;
      reB[r0] = ctl ? n0r : r0r; imB[r0] = ctl ? n0i : r0i;
      reB[r1] = ctl ? n1r : r1r; imB[r1] = ctl ? n1i : r1i; }
  }
}

template <int CM, int TM> __device__ __forceinline__
void crx_rr2(float (&reA)[8], float (&imA)[8], float (&reB)[8], float (&imB)[8],
             float co, float si) {
#pragma unroll
  for (int r0 = 0; r0 < 8; ++r0) if ((r0 & CM) && !(r0 & TM)) {
    const int r1 = r0 | TM;
    { const float r0r = reA[r0], r0i = imA[r0], r1r = reA[r1], r1i = imA[r1];
      reA[r0] = co*r0r + si*r1i; imA[r0] = co*r0i - si*r1r;
      reA[r1] = co*r1r + si*r0i; imA[r1] = co*r1i - si*r0r; }
    { const float r0r = reB[r0], r0i = imB[r0], r1r = reB[r1], r1i = imB[r1];
      reB[r0] = co*r0r + si*r1i; imB[r0] = co*r0i - si*r1r;
      reB[r1] = co*r1r + si*r0i; imB[r1] = co*r1i - si*r0r; }
  }
}

__global__ __launch_bounds__(256, 4) void qcnn_fused(const float* __restrict__ x,
                                                     const float* __restrict__ w,
                                                     float* __restrict__ feats) {
  __shared__ float  wenc[9];    // w[0..8] raw (folded into encoding angle)
  __shared__ float  wrzl[6];    // 0.5*w[9+q] for lane qubits {1,2,4,5,7,8}
  __shared__ float2 rztab[8];   // combined reg-qubit RZ phase per r
  __shared__ float2 g[24];      // (cos,sin)(w[18+k]/2) for all later gates

  const int tid = threadIdx.x;
  if (tid < 9) {
    wenc[tid] = w[tid];
  } else if (tid < 15) {
    const int qmap[6] = {1, 2, 4, 5, 7, 8};
    wrzl[tid - 9] = 0.5f * w[9 + qmap[tid - 9]];
  } else if (tid >= 16 && tid < 24) {
    const int r = tid - 16;
    const float ph = ((r & 1) ? 0.5f : -0.5f) * w[9]
                   + ((r & 2) ? 0.5f : -0.5f) * w[12]
                   + ((r & 4) ? 0.5f : -0.5f) * w[15];
    float s, c; __sincosf(ph, &s, &c);
    rztab[r] = make_float2(c, s);
  } else if (tid >= 24 && tid < 48) {
    float s, c; __sincosf(0.5f * w[18 + tid - 24], &s, &c);
    g[tid - 24] = make_float2(c, s);
  }
  __syncthreads();

  const int lane = tid & 63;
  const int wv = tid >> 6;
  const unsigned pA = (blockIdx.x * 4u + wv) * 2u;   // even patch
  const unsigned pB = pA + 1u;
  const unsigned bA = pA / 676u, remA = pA - bA * 676u;
  const unsigned bB = pB / 676u, remB = pB - bB * 676u;

  // lanes 0..8: patch A encoding sincos; lanes 9..17: patch B
  float c_enc = 0.0f, s_enc = 0.0f;
  if (lane < 18) {
    const int isB = lane >= 9;
    const int q = isB ? lane - 9 : lane;
    const unsigned bb = isB ? bB : bA;
    const unsigned rm = isB ? remB : remA;
    const unsigned ii = rm / 26u, jj = rm - ii * 26u;
    const int di = q / 3, dj = q - di * 3;
    const float xv = x[bb * 784u + (ii + di) * 28u + (jj + dj)];
    const float ang = fmaf(xv, 3.14159265358979323846f, wenc[q]) * 0.5f;
    __sincosf(ang, &s_enc, &c_enc);
  }
  float cqA[9], sqA[9], cqB[9], sqB[9];
#pragma unroll
  for (int q = 0; q < 9; ++q) {
    cqA[q] = __shfl(c_enc, q, 64);     sqA[q] = __shfl(s_enc, q, 64);
    cqB[q] = __shfl(c_enc, 9 + q, 64); sqB[q] = __shfl(s_enc, 9 + q, 64);
  }

  // lane part of conv1-RZ phase: patch-independent, computed once
  const float ph = (lane & 1  ? wrzl[0] : -wrzl[0])
                 + (lane & 2  ? wrzl[1] : -wrzl[1])
                 + (lane & 4  ? wrzl[2] : -wrzl[2])
                 + (lane & 8  ? wrzl[3] : -wrzl[3])
                 + (lane & 16 ? wrzl[4] : -wrzl[4])
                 + (lane & 32 ? wrzl[5] : -wrzl[5]);
  float sl, cl; __sincosf(ph, &sl, &cl);
  float ccr[8], ssr[8];
#pragma unroll
  for (int r = 0; r < 8; ++r) {
    ccr[r] = cl * rztab[r].x - sl * rztab[r].y;   // cos(ph + phr)
    ssr[r] = sl * rztab[r].x + cl * rztab[r].y;   // sin(ph + phr)
  }

  // product-state lane factors
  float FA = fsel(lane & 1,  sqA[1], cqA[1]);
  FA      *= fsel(lane & 2,  sqA[2], cqA[2]);
  FA      *= fsel(lane & 4,  sqA[4], cqA[4]);
  FA      *= fsel(lane & 8,  sqA[5], cqA[5]);
  FA      *= fsel(lane & 16, sqA[7], cqA[7]);
  FA      *= fsel(lane & 32, sqA[8], cqA[8]);
  float FB = fsel(lane & 1,  sqB[1], cqB[1]);
  FB      *= fsel(lane & 2,  sqB[2], cqB[2]);
  FB      *= fsel(lane & 4,  sqB[4], cqB[4]);
  FB      *= fsel(lane & 8,  sqB[5], cqB[5]);
  FB      *= fsel(lane & 16, sqB[7], cqB[7]);
  FB      *= fsel(lane & 32, sqB[8], cqB[8]);

  // state after encoding + conv1 RY + conv1 RZ
  float reA[8], imA[8], reB[8], imB[8];
#pragma unroll
  for (int r = 0; r < 8; ++r) {
    const float prA = (r & 1 ? sqA[0] : cqA[0]) * (r & 2 ? sqA[3] : cqA[3]) * (r & 4 ? sqA[6] : cqA[6]);
    const float prB = (r & 1 ? sqB[0] : cqB[0]) * (r & 2 ? sqB[3] : cqB[3]) * (r & 4 ? sqB[6] : cqB[6]);
    const float AA = FA * prA, AB = FB * prB;
    reA[r] = AA * ccr[r]; imA[r] = AA * ssr[r];
    reB[r] = AB * ccr[r]; imB[r] = AB * ssr[r];
  }

  // ring CNOT (0,1)(1,2)...(8,0) under the remap
  cx_rl2<1, 1>(reA, imA, reB, imB);            // CX(0,1)
  cx_ll2<1, 2>(reA, imA, reB, imB, lane);      // CX(1,2)
  cx_lr2<2, 2>(reA, imA, reB, imB, lane);      // CX(2,3)
  cx_rl2<2, 4>(reA, imA, reB, imB);            // CX(3,4)
  cx_ll2<4, 8>(reA, imA, reB, imB, lane);      // CX(4,5)
  cx_lr2<8, 4>(reA, imA, reB, imB, lane);      // CX(5,6)
  cx_rl2<4, 16>(reA, imA, reB, imB);           // CX(6,7)
  cx_ll2<16, 32>(reA, imA, reB, imB, lane);    // CX(7,8)
  cx_lr2<32, 1>(reA, imA, reB, imB, lane);     // CX(8,0)

  // pool1 (register-local)
  crx_lr2<1,  1>(reA, imA, reB, imB, lane, g[0].x, g[0].y);
  crx_lr2<2,  1>(reA, imA, reB, imB, lane, g[1].x, g[1].y);
  crx_lr2<4,  2>(reA, imA, reB, imB, lane, g[2].x, g[2].y);
  crx_lr2<8,  2>(reA, imA, reB, imB, lane, g[3].x, g[3].y);
  crx_lr2<16, 4>(reA, imA, reB, imB, lane, g[4].x, g[4].y);
  crx_lr2<32, 4>(reA, imA, reB, imB, lane, g[5].x, g[5].y);
  // conv2 on {0,3,6} -> reg bits {1,2,4}
  ry2<1>(reA, imA, reB, imB, g[6].x, g[6].y);
  ry2<2>(reA, imA, reB, imB, g[7].x, g[7].y);
  ry2<4>(reA, imA, reB, imB, g[8].x, g[8].y);
  rz2<1>(reA, imA, reB, imB, g[9].x, g[9].y);
  rz2<2>(reA, imA, reB, imB, g[10].x, g[10].y);
  rz2<4>(reA, imA, reB, imB, g[11].x, g[11].y);
  cx_rr2<1, 2>(reA, imA, reB, imB);
  cx_rr2<2, 4>(reA, imA, reB, imB);
  cx_rr2<4, 1>(reA, imA, reB, imB);
  ry2<1>(reA, imA, reB, imB, g[12].x, g[12].y);
  rz2<2>(reA, imA, reB, imB, g[13].x, g[13].y);
  // pool2
  crx_rr2<2, 1>(reA, imA, reB, imB, g[14].x, g[14].y);
  crx_rr2<2, 4>(reA, imA, reB, imB, g[15].x, g[15].y);
  ry2<1>(reA, imA, reB, imB, g[16].x, g[16].y);
  ry2<4>(reA, imA, reB, imB, g[17].x, g[17].y);
  // conv3
  ry2<1>(reA, imA, reB, imB, g[18].x, g[18].y);
  ry2<4>(reA, imA, reB, imB, g[19].x, g[19].y);
  cx_rr2<1, 4>(reA, imA, reB, imB);
  rz2<1>(reA, imA, reB, imB, g[20].x, g[20].y);
  rz2<4>(reA, imA, reB, imB, g[21].x, g[21].y);
  // pool3
  crx_rr2<4, 1>(reA, imA, reB, imB, g[22].x, g[22].y);
  ry2<1>(reA, imA, reB, imB, g[23].x, g[23].y);

  // <X>,<Y>,<Z> on qubit 0 = reg bit 0, both patches
  float zrA = 0.f, ziA = 0.f, ezA = 0.f, zrB = 0.f, ziB = 0.f, ezB = 0.f;
#pragma unroll
  for (int r0 = 0; r0 < 8; r0 += 2) {
    const int r1 = r0 + 1;
    zrA += reA[r0]*reA[r1] + imA[r0]*imA[r1];
    ziA += reA[r0]*imA[r1] - imA[r0]*reA[r1];
    ezA += reA[r0]*reA[r0] + imA[r0]*imA[r0] - reA[r1]*reA[r1] - imA[r1]*imA[r1];
    zrB += reB[r0]*reB[r1] + imB[r0]*imB[r1];
    ziB += reB[r0]*imB[r1] - imB[r0]*reB[r1];
    ezB += reB[r0]*reB[r0] + imB[r0]*imB[r0] - reB[r1]*reB[r1] - imB[r1]*imB[r1];
  }
#pragma unroll
  for (int m = 1; m < 64; m <<= 1) {
    zrA += shx(zrA, m); ziA += shx(ziA, m); ezA += shx(ezA, m);
    zrB += shx(zrB, m); ziB += shx(ziB, m); ezB += shx(ezB, m);
  }
  if (lane == 0) {
    feats[pA * 3u + 0u] = 2.0f * zrA;
    feats[pA * 3u + 1u] = 2.0f * ziA;
    feats[pA * 3u + 2u] = ezA;
  } else if (lane == 1) {
    feats[pB * 3u + 0u] = 2.0f * zrB;
    feats[pB * 3u + 1u] = 2.0f * ziB;
    feats[pB * 3u + 2u] = ezB;
  }
}

// out[b,c] = fc_b[c] + dot(feats[b,:], fc_w[c,:]) over 2028 elements.
__global__ __launch_bounds__(256) void fc_kernel(const float* __restrict__ feats,
                                                 const float* __restrict__ fc_w,
                                                 const float* __restrict__ fc_b,
                                                 float* __restrict__ out) {
  const int b = blockIdx.x / 10, c = blockIdx.x - b * 10;
  const float* f = feats + b * 2028;
  const float* wr = fc_w + c * 2028;
  float acc = 0.0f;
  for (int k = threadIdx.x; k < 2028; k += 256) acc += f[k] * wr[k];
#pragma unroll
  for (int m = 1; m < 64; m <<= 1) acc += __shfl_xor(acc, m, 64);
  __shared__ float sbuf[4];
  const int lane = threadIdx.x & 63, wv = threadIdx.x >> 6;
  if (lane == 0) sbuf[wv] = acc;
  __syncthreads();
  if (threadIdx.x == 0) out[b * 10 + c] = sbuf[0] + sbuf[1] + sbuf[2] + sbuf[3] + fc_b[c];
}

extern "C" void kernel_launch(void* const* d_in, const int* in_sizes, int n_in,
                              void* d_out, int out_size, void* d_ws, size_t ws_size,
                              hipStream_t stream) {
  const float* x    = (const float*)d_in[0];   // (B,1,28,28)
  const float* w    = (const float*)d_in[1];   // (42,)
  const float* fc_w = (const float*)d_in[2];   // (10, 2028)
  const float* fc_b = (const float*)d_in[3];   // (10,)
  float* out = (float*)d_out;                  // (B, 10)

  const int B = in_sizes[0] / 784;             // 8
  const int npatch = B * 676;                  // 5408; divisible by 8

  float* feats = (float*)d_ws;                 // npatch*3 floats, fully written below

  qcnn_fused<<<npatch / 8, 256, 0, stream>>>(x, w, feats);
  fc_kernel<<<B * 10, 256, 0, stream>>>(feats, fc_w, fc_b, out);
}

// Round 5
// 75.588 us; speedup vs baseline: 1.0522x; 1.0522x over previous
//
#include <hip/hip_runtime.h>

// One wavefront = one 9-qubit patch circuit (round-3 structure; round-4's
// 2-patch/wave ILP experiment REGRESSED: TLP 5.3->2.6 waves/SIMD lost more
// than ILP gained — keep 1 patch/wave).
//
// Qubit -> bit remap:
//   qubit 0 -> reg bit 0   qubit 3 -> reg bit 1   qubit 6 -> reg bit 2
//   qubit 1 -> lane bit 0  qubit 2 -> lane bit 1  qubit 4 -> lane bit 2
//   qubit 5 -> lane bit 3  qubit 7 -> lane bit 4  qubit 8 -> lane bit 5
//
// Algebraic folds (this round's additions marked *):
//   enc RY + conv1 RY on |0>  -> real product state (direct construction)
//   9x conv1 RZ               -> one diagonal phase (lane part + reg table)
// * pool1 (6 CRX, commuting per target) -> 3 per-lane RX, 4-entry LUT/axis
// * conv2..pool3 (20 lane-independent reg-qubit gates) -> ONE wave-uniform
//   8x8 complex matrix M (built per block by 8 threads, 512B LDS, broadcast
//   reads) -> single matvec, chain depth 20 gates -> ~8 FMA.
//   measure: ez = 2*sum_even|v|^2 - 1 (norm preserved).
//
// Round-2 lesson: no fused atomicAdd epilogue (coherence-point serialization).
// Harness's 256MB d_ws poison-fill (~39.5us) is a fixed floor we can't touch.

__device__ __forceinline__ float shx(float v, int m) { return __shfl_xor(v, m, 64); }
__device__ __forceinline__ float fsel(int c, float a, float b) { return c ? a : b; }

template <int TM> __device__ __forceinline__
void ry_r(float (&re)[8], float (&im)[8], float c, float s) {
#pragma unroll
  for (int r0 = 0; r0 < 8; ++r0) if (!(r0 & TM)) {
    const int r1 = r0 | TM;
    float a = re[r0], bb = re[r1];
    re[r0] = c * a - s * bb; re[r1] = s * a + c * bb;
    a = im[r0]; bb = im[r1];
    im[r0] = c * a - s * bb; im[r1] = s * a + c * bb;
  }
}

template <int TM> __device__ __forceinline__
void rz_r(float (&re)[8], float (&im)[8], float c, float s) {
#pragma unroll
  for (int r = 0; r < 8; ++r) {
    const float sg = (r & TM) ? s : -s;
    const float a = re[r], bb = im[r];
    re[r] = c * a - sg * bb;
    im[r] = c * bb + sg * a;
  }
}

template <int CM, int TM> __device__ __forceinline__
void cx_rr(float (&re)[8], float (&im)[8]) {
#pragma unroll
  for (int r0 = 0; r0 < 8; ++r0) if ((r0 & CM) && !(r0 & TM)) {
    const int r1 = r0 | TM;
    float t = re[r0]; re[r0] = re[r1]; re[r1] = t;
    t = im[r0]; im[r0] = im[r1]; im[r1] = t;
  }
}

template <int CL, int TM> __device__ __forceinline__
void cx_lr(float (&re)[8], float (&im)[8], int lane) {
  const bool ctl = (lane & CL) != 0;
#pragma unroll
  for (int r0 = 0; r0 < 8; ++r0) if (!(r0 & TM)) {
    const int r1 = r0 | TM;
    float a0 = re[r0], a1 = re[r1];
    re[r0] = ctl ? a1 : a0; re[r1] = ctl ? a0 : a1;
    a0 = im[r0]; a1 = im[r1];
    im[r0] = ctl ? a1 : a0; im[r1] = ctl ? a0 : a1;
  }
}

template <int CM, int TL> __device__ __forceinline__
void cx_rl(float (&re)[8], float (&im)[8]) {
#pragma unroll
  for (int r = 0; r < 8; ++r) if (r & CM) {
    re[r] = shx(re[r], TL);
    im[r] = shx(im[r], TL);
  }
}

template <int CL, int TL> __device__ __forceinline__
void cx_ll(float (&re)[8], float (&im)[8], int lane) {
  const bool ctl = (lane & CL) != 0;
#pragma unroll
  for (int r = 0; r < 8; ++r) {
    const float orr = shx(re[r], TL), oii = shx(im[r], TL);
    re[r] = ctl ? orr : re[r];
    im[r] = ctl ? oii : im[r];
  }
}

template <int CM, int TM> __device__ __forceinline__
void crx_rr(float (&re)[8], float (&im)[8], float co, float si) {
#pragma unroll
  for (int r0 = 0; r0 < 8; ++r0) if ((r0 & CM) && !(r0 & TM)) {
    const int r1 = r0 | TM;
    const float r0r = re[r0], r0i = im[r0], r1r = re[r1], r1i = im[r1];
    re[r0] = co * r0r + si * r1i; im[r0] = co * r0i - si * r1r;
    re[r1] = co * r1r + si * r0i; im[r1] = co * r1i - si * r0r;
  }
}

// per-lane RX on reg-bit TM: [[c,-is],[-is,c]] with lane-dependent (c,s)
template <int TM> __device__ __forceinline__
void rx_l(float (&re)[8], float (&im)[8], float c, float s) {
#pragma unroll
  for (int r0 = 0; r0 < 8; ++r0) if (!(r0 & TM)) {
    const int r1 = r0 | TM;
    const float r0r = re[r0], r0i = im[r0], r1r = re[r1], r1i = im[r1];
    re[r0] = c * r0r + s * r1i;  im[r0] = c * r0i - s * r1r;
    re[r1] = c * r1r + s * r0i;  im[r1] = c * r1i - s * r0r;
  }
}

__global__ __launch_bounds__(256) void qcnn_fused(const float* __restrict__ x,
                                                  const float* __restrict__ w,
                                                  float* __restrict__ feats) {
  __shared__ float  wenc[9];      // w[0..8] raw (folded into encoding angle)
  __shared__ float  wrzl[6];      // 0.5*w[9+q] for lane qubits {1,2,4,5,7,8}
  __shared__ float2 rztab[8];     // combined reg-qubit RZ phase per r
  __shared__ float2 g[24];        // (cos,sin)(w[18+k]/2)
  __shared__ float2 rxtab[3][4];  // pool1 folded RX: per axis, 4 angle combos
  __shared__ float2 Msh[8][8];    // conv2..pool3 composed 8x8 matrix

  const int tid = threadIdx.x;
  if (tid < 9) {
    wenc[tid] = w[tid];
  } else if (tid < 15) {
    const int qmap[6] = {1, 2, 4, 5, 7, 8};
    wrzl[tid - 9] = 0.5f * w[9 + qmap[tid - 9]];
  } else if (tid >= 16 && tid < 24) {
    const int r = tid - 16;
    const float ph = ((r & 1) ? 0.5f : -0.5f) * w[9]
                   + ((r & 2) ? 0.5f : -0.5f) * w[12]
                   + ((r & 4) ? 0.5f : -0.5f) * w[15];
    float s, c; __sincosf(ph, &s, &c);
    rztab[r] = make_float2(c, s);
  } else if (tid >= 24 && tid < 48) {
    float s, c; __sincosf(0.5f * w[18 + tid - 24], &s, &c);
    g[tid - 24] = make_float2(c, s);
  } else if (tid >= 48 && tid < 60) {
    // pool1 LUT: axis a targets reg bit a; controls contribute additively.
    const int k = tid - 48, a = k >> 2, cb = k & 3;
    float th = 0.0f;
    if (cb & 1) th += w[18 + 2 * a];
    if (cb & 2) th += w[19 + 2 * a];
    float s, c; __sincosf(0.5f * th, &s, &c);
    rxtab[a][cb] = make_float2(c, s);
  }
  __syncthreads();

  // Build M = conv2..pool3 (lane-independent reg-qubit gates): thread j
  // evolves basis column e_j through the exact round-3 gate sequence.
  if (tid < 8) {
    float re[8], im[8];
#pragma unroll
    for (int r = 0; r < 8; ++r) { re[r] = (r == tid) ? 1.0f : 0.0f; im[r] = 0.0f; }
    ry_r<1>(re, im, g[6].x, g[6].y);     // RY q0 w24
    ry_r<2>(re, im, g[7].x, g[7].y);     // RY q3 w25
    ry_r<4>(re, im, g[8].x, g[8].y);     // RY q6 w26
    rz_r<1>(re, im, g[9].x, g[9].y);     // RZ q0 w27
    rz_r<2>(re, im, g[10].x, g[10].y);   // RZ q3 w28
    rz_r<4>(re, im, g[11].x, g[11].y);   // RZ q6 w29
    cx_rr<1, 2>(re, im);                 // CX(0,3)
    cx_rr<2, 4>(re, im);                 // CX(3,6)
    cx_rr<4, 1>(re, im);                 // CX(6,0)
    ry_r<1>(re, im, g[12].x, g[12].y);   // RY q0 w30
    rz_r<2>(re, im, g[13].x, g[13].y);   // RZ q3 w31
    crx_rr<2, 1>(re, im, g[14].x, g[14].y);  // (3,0) w32
    crx_rr<2, 4>(re, im, g[15].x, g[15].y);  // (3,6) w33
    ry_r<1>(re, im, g[16].x, g[16].y);   // RY q0 w34
    ry_r<4>(re, im, g[17].x, g[17].y);   // RY q6 w35
    ry_r<1>(re, im, g[18].x, g[18].y);   // RY q0 w36
    ry_r<4>(re, im, g[19].x, g[19].y);   // RY q6 w37
    cx_rr<1, 4>(re, im);                 // CX(0,6)
    rz_r<1>(re, im, g[20].x, g[20].y);   // RZ q0 w38
    rz_r<4>(re, im, g[21].x, g[21].y);   // RZ q6 w39
    crx_rr<4, 1>(re, im, g[22].x, g[22].y);  // (6,0) w40
    ry_r<1>(re, im, g[23].x, g[23].y);   // RY q0 w41
#pragma unroll
    for (int i = 0; i < 8; ++i) Msh[i][tid] = make_float2(re[i], im[i]);
  }
  __syncthreads();

  const int lane = tid & 63;
  const unsigned p = blockIdx.x * 4u + (tid >> 6);   // patch id (grid exact)
  const unsigned b = p / 676u;
  const unsigned rem = p - b * 676u;
  const unsigned i = rem / 26u, j = rem - i * 26u;
  const float* xb = x + b * 784u;

  // lanes 0..8: sincos of combined (encoding + conv1 RY) half-angle
  float c_enc = 0.0f, s_enc = 0.0f;
  if (lane < 9) {
    const int di = lane / 3, dj = lane - di * 3;
    const float ang = fmaf(xb[(i + di) * 28u + (j + dj)],
                           3.14159265358979323846f, wenc[lane]) * 0.5f;
    __sincosf(ang, &s_enc, &c_enc);
  }
  float cq[9], sq[9];
#pragma unroll
  for (int q = 0; q < 9; ++q) { cq[q] = __shfl(c_enc, q, 64); sq[q] = __shfl(s_enc, q, 64); }

  // product-state lane factor over lane qubits {1,2,4,5,7,8}
  float F = fsel(lane & 1,  sq[1], cq[1]);
  F      *= fsel(lane & 2,  sq[2], cq[2]);
  F      *= fsel(lane & 4,  sq[4], cq[4]);
  F      *= fsel(lane & 8,  sq[5], cq[5]);
  F      *= fsel(lane & 16, sq[7], cq[7]);
  F      *= fsel(lane & 32, sq[8], cq[8]);
  // lane part of the combined conv1-RZ phase
  const float ph = (lane & 1  ? wrzl[0] : -wrzl[0])
                 + (lane & 2  ? wrzl[1] : -wrzl[1])
                 + (lane & 4  ? wrzl[2] : -wrzl[2])
                 + (lane & 8  ? wrzl[3] : -wrzl[3])
                 + (lane & 16 ? wrzl[4] : -wrzl[4])
                 + (lane & 32 ? wrzl[5] : -wrzl[5]);
  float sl, cl; __sincosf(ph, &sl, &cl);

  // state after encoding + conv1 RY + conv1 RZ
  float re[8], im[8];
#pragma unroll
  for (int r = 0; r < 8; ++r) {
    const float pr = (r & 1 ? sq[0] : cq[0]) * (r & 2 ? sq[3] : cq[3]) * (r & 4 ? sq[6] : cq[6]);
    const float A = F * pr;
    const float cr = rztab[r].x, sr = rztab[r].y;
    const float cc = cl * cr - sl * sr;
    const float ss = sl * cr + cl * sr;
    re[r] = A * cc;
    im[r] = A * ss;
  }

  // ring CNOT (0,1)(1,2)...(8,0) under the remap
  cx_rl<1, 1>(re, im);            // CX(0,1)
  cx_ll<1, 2>(re, im, lane);      // CX(1,2)
  cx_lr<2, 2>(re, im, lane);      // CX(2,3)
  cx_rl<2, 4>(re, im);            // CX(3,4)
  cx_ll<4, 8>(re, im, lane);      // CX(4,5)
  cx_lr<8, 4>(re, im, lane);      // CX(5,6)
  cx_rl<4, 16>(re, im);           // CX(6,7)
  cx_ll<16, 32>(re, im, lane);    // CX(7,8)
  cx_lr<32, 1>(re, im, lane);     // CX(8,0)

  // pool1 folded: per-lane RX on each reg axis (angle LUT by 2 control bits)
  const float2 x0 = rxtab[0][lane & 3];
  const float2 x1 = rxtab[1][(lane >> 2) & 3];
  const float2 x2 = rxtab[2][(lane >> 4) & 3];
  rx_l<1>(re, im, x0.x, x0.y);
  rx_l<2>(re, im, x1.x, x1.y);
  rx_l<4>(re, im, x2.x, x2.y);

  // conv2..pool3 in one shot: v = M u (M wave-uniform, LDS broadcast reads)
  float nre[8], nim[8];
#pragma unroll
  for (int oi = 0; oi < 8; ++oi) {
    float ar = 0.0f, ai = 0.0f;
#pragma unroll
    for (int jj = 0; jj < 8; ++jj) {
      const float2 m = Msh[oi][jj];
      ar = fmaf(m.x, re[jj], ar);  ar = fmaf(-m.y, im[jj], ar);
      ai = fmaf(m.x, im[jj], ai);  ai = fmaf(m.y, re[jj], ai);
    }
    nre[oi] = ar; nim[oi] = ai;
  }

  // <X>,<Y>,<Z> on qubit 0 = reg bit 0; ez via 2*P(even)-1 (norm preserved)
  float zr = 0.f, zi = 0.f, pe = 0.f;
#pragma unroll
  for (int r0 = 0; r0 < 8; r0 += 2) {
    const int r1 = r0 + 1;
    zr += nre[r0] * nre[r1] + nim[r0] * nim[r1];
    zi += nre[r0] * nim[r1] - nim[r0] * nre[r1];
    pe += nre[r0] * nre[r0] + nim[r0] * nim[r0];
  }
#pragma unroll
  for (int m = 1; m < 64; m <<= 1) { zr += shx(zr, m); zi += shx(zi, m); pe += shx(pe, m); }

  if (lane == 0) {
    feats[p * 3u + 0u] = 2.0f * zr;          // <X>
    feats[p * 3u + 1u] = 2.0f * zi;          // <Y>
    feats[p * 3u + 2u] = 2.0f * pe - 1.0f;   // <Z>
  }
}

// out[b,c] = fc_b[c] + dot(feats[b,:], fc_w[c,:]) over 2028 elements.
__global__ __launch_bounds__(256) void fc_kernel(const float* __restrict__ feats,
                                                 const float* __restrict__ fc_w,
                                                 const float* __restrict__ fc_b,
                                                 float* __restrict__ out) {
  const int b = blockIdx.x / 10, c = blockIdx.x - b * 10;
  const float* f = feats + b * 2028;
  const float* wr = fc_w + c * 2028;
  float acc = 0.0f;
  for (int k = threadIdx.x; k < 2028; k += 256) acc += f[k] * wr[k];
#pragma unroll
  for (int m = 1; m < 64; m <<= 1) acc += __shfl_xor(acc, m, 64);
  __shared__ float sbuf[4];
  const int lane = threadIdx.x & 63, wv = threadIdx.x >> 6;
  if (lane == 0) sbuf[wv] = acc;
  __syncthreads();
  if (threadIdx.x == 0) out[b * 10 + c] = sbuf[0] + sbuf[1] + sbuf[2] + sbuf[3] + fc_b[c];
}

extern "C" void kernel_launch(void* const* d_in, const int* in_sizes, int n_in,
                              void* d_out, int out_size, void* d_ws, size_t ws_size,
                              hipStream_t stream) {
  const float* x    = (const float*)d_in[0];   // (B,1,28,28)
  const float* w    = (const float*)d_in[1];   // (42,)
  const float* fc_w = (const float*)d_in[2];   // (10, 2028)
  const float* fc_b = (const float*)d_in[3];   // (10,)
  float* out = (float*)d_out;                  // (B, 10)

  const int B = in_sizes[0] / 784;             // 8
  const int npatch = B * 676;                  // 5408; divisible by 4

  float* feats = (float*)d_ws;                 // npatch*3 floats, fully written

  qcnn_fused<<<npatch / 4, 256, 0, stream>>>(x, w, feats);
  fc_kernel<<<B * 10, 256, 0, stream>>>(feats, fc_w, fc_b, out);
}

// Round 6
// 70.500 us; speedup vs baseline: 1.1281x; 1.0722x over previous
//
#include <hip/hip_runtime.h>

// One wavefront = one 9-qubit patch circuit.
//
// Qubit -> bit remap:
//   qubit 0 -> reg bit 0 (R0)  qubit 3 -> reg bit 1 (R1)  qubit 6 -> reg bit 2 (R2)
//   qubit 1 -> lane bit 0      qubit 2 -> lane bit 1      qubit 4 -> lane bit 2
//   qubit 5 -> lane bit 3      qubit 7 -> lane bit 4      qubit 8 -> lane bit 5
//
// Full algebraic pipeline (round-6: ring CNOT eliminated analytically):
//   1) enc RY + conv1 RY on |0>      -> per-qubit real (c,s)
//   2) conv1 RZ                       -> folds per-qubit: tau_q(b) = (b?s:c)*e^{i sgn(b) wz_q/2}
//   3) ring CNOT is GF(2)-linear: b'_k = b0^..^bk (k>=1), b'_0 = b1^..^b8.
//      amp_after(h) = amp_before(g^-1(h)); with our layout the inverse bits are
//        b0=R0^l5  b1=R0^(l0^l5)  b2=l0^l1  b3=R1^l1  b4=R1^l2
//        b5=l2^l3  b6=R2^l3       b7=R2^l4  b8=l4^l5
//      => post-ring state is a per-lane PRODUCT p0(R0) x p1(R1) x p2(R2)
//         (qubit pairs {0,1},{3,4},{6,7} + lane-only {2,5,8} folded in).
//      ZERO cross-lane ops for encode+conv1+ring.
//   4) pool1 (6 CRX, controls = pure lane bits) -> per-lane RX applied to the
//      three 2-vectors directly (8 FMA each).
//   5) conv2..pool3 (20 lane-independent reg gates) -> one wave-uniform 8x8
//      matrix M in LDS (float4-packed rows, broadcast ds_read_b128), built by
//      8 threads OVERLAPPED with the encode path (barrier moved before matvec).
//   6) measure qubit0: z = sum_even conj(v0)v1, ez = 2*P(even)-1.
//
// Round-2 lesson: no atomicAdd epilogue. Round-4 lesson: keep 1 patch/wave
// (TLP > ILP here). Harness's 256MB d_ws poison fill (~40us) is a fixed floor.

__device__ __forceinline__ float shx(float v, int m) { return __shfl_xor(v, m, 64); }

__device__ __forceinline__ float2 cmul(float2 a, float2 b) {
  return make_float2(a.x * b.x - a.y * b.y, a.x * b.y + a.y * b.x);
}

// ---- single-state reg-qubit gates (used only for the 8-thread M build) ----
template <int TM> __device__ __forceinline__
void ry_r(float (&re)[8], float (&im)[8], float c, float s) {
#pragma unroll
  for (int r0 = 0; r0 < 8; ++r0) if (!(r0 & TM)) {
    const int r1 = r0 | TM;
    float a = re[r0], bb = re[r1];
    re[r0] = c * a - s * bb; re[r1] = s * a + c * bb;
    a = im[r0]; bb = im[r1];
    im[r0] = c * a - s * bb; im[r1] = s * a + c * bb;
  }
}
template <int TM> __device__ __forceinline__
void rz_r(float (&re)[8], float (&im)[8], float c, float s) {
#pragma unroll
  for (int r = 0; r < 8; ++r) {
    const float sg = (r & TM) ? s : -s;
    const float a = re[r], bb = im[r];
    re[r] = c * a - sg * bb;
    im[r] = c * bb + sg * a;
  }
}
template <int CM, int TM> __device__ __forceinline__
void cx_rr(float (&re)[8], float (&im)[8]) {
#pragma unroll
  for (int r0 = 0; r0 < 8; ++r0) if ((r0 & CM) && !(r0 & TM)) {
    const int r1 = r0 | TM;
    float t = re[r0]; re[r0] = re[r1]; re[r1] = t;
    t = im[r0]; im[r0] = im[r1]; im[r1] = t;
  }
}
template <int CM, int TM> __device__ __forceinline__
void crx_rr(float (&re)[8], float (&im)[8], float co, float si) {
#pragma unroll
  for (int r0 = 0; r0 < 8; ++r0) if ((r0 & CM) && !(r0 & TM)) {
    const int r1 = r0 | TM;
    const float r0r = re[r0], r0i = im[r0], r1r = re[r1], r1i = im[r1];
    re[r0] = co * r0r + si * r1i; im[r0] = co * r0i - si * r1r;
    re[r1] = co * r1r + si * r0i; im[r1] = co * r1i - si * r0r;
  }
}

__global__ __launch_bounds__(256) void qcnn_fused(const float* __restrict__ x,
                                                  const float* __restrict__ w,
                                                  float* __restrict__ feats) {
  __shared__ float  wenc[9];      // w[0..8] (folded into encoding angle)
  __shared__ float2 zcs[9];       // (cos,sin)(w[9+q]/2) — conv1 RZ per qubit
  __shared__ float2 g[24];        // (cos,sin)(w[18+k]/2) — later gates (M build)
  __shared__ float2 rxtab[3][4];  // pool1 folded RX LUT
  __shared__ float4 Msh[8][4];    // M row-major, 2 complex entries per float4

  const int tid = threadIdx.x;
  if (tid < 9) {
    wenc[tid] = w[tid];
  } else if (tid >= 16 && tid < 25) {
    float s, c; __sincosf(0.5f * w[9 + (tid - 16)], &s, &c);
    zcs[tid - 16] = make_float2(c, s);
  } else if (tid >= 32 && tid < 56) {
    float s, c; __sincosf(0.5f * w[18 + (tid - 32)], &s, &c);
    g[tid - 32] = make_float2(c, s);
  } else if (tid >= 56 && tid < 68) {
    const int k = tid - 56, a = k >> 2, cb = k & 3;
    float th = 0.0f;
    if (cb & 1) th += w[18 + 2 * a];
    if (cb & 2) th += w[19 + 2 * a];
    float s, c; __sincosf(0.5f * th, &s, &c);
    rxtab[a][cb] = make_float2(c, s);
  }
  __syncthreads();

  // ---- M build (8 threads of wave 0); other waves overlap with encode ----
  if (tid < 8) {
    float re[8], im[8];
#pragma unroll
    for (int r = 0; r < 8; ++r) { re[r] = (r == tid) ? 1.0f : 0.0f; im[r] = 0.0f; }
    ry_r<1>(re, im, g[6].x, g[6].y);         // RY q0 w24
    ry_r<2>(re, im, g[7].x, g[7].y);         // RY q3 w25
    ry_r<4>(re, im, g[8].x, g[8].y);         // RY q6 w26
    rz_r<1>(re, im, g[9].x, g[9].y);         // RZ q0 w27
    rz_r<2>(re, im, g[10].x, g[10].y);       // RZ q3 w28
    rz_r<4>(re, im, g[11].x, g[11].y);       // RZ q6 w29
    cx_rr<1, 2>(re, im);                     // CX(0,3)
    cx_rr<2, 4>(re, im);                     // CX(3,6)
    cx_rr<4, 1>(re, im);                     // CX(6,0)
    ry_r<1>(re, im, g[12].x, g[12].y);       // RY q0 w30
    rz_r<2>(re, im, g[13].x, g[13].y);       // RZ q3 w31
    crx_rr<2, 1>(re, im, g[14].x, g[14].y);  // (3,0) w32
    crx_rr<2, 4>(re, im, g[15].x, g[15].y);  // (3,6) w33
    ry_r<1>(re, im, g[16].x, g[16].y);       // RY q0 w34
    ry_r<4>(re, im, g[17].x, g[17].y);       // RY q6 w35
    ry_r<1>(re, im, g[18].x, g[18].y);       // RY q0 w36
    ry_r<4>(re, im, g[19].x, g[19].y);       // RY q6 w37
    cx_rr<1, 4>(re, im);                     // CX(0,6)
    rz_r<1>(re, im, g[20].x, g[20].y);       // RZ q0 w38
    rz_r<4>(re, im, g[21].x, g[21].y);       // RZ q6 w39
    crx_rr<4, 1>(re, im, g[22].x, g[22].y);  // (6,0) w40
    ry_r<1>(re, im, g[23].x, g[23].y);       // RY q0 w41
    // column tid -> packed rows: Msh[i][tid>>1] components (2*(tid&1), +1)
    float* mp = (float*)&Msh[0][0];
#pragma unroll
    for (int i = 0; i < 8; ++i) {
      mp[i * 16 + (tid >> 1) * 4 + 2 * (tid & 1) + 0] = re[i];
      mp[i * 16 + (tid >> 1) * 4 + 2 * (tid & 1) + 1] = im[i];
    }
  }

  // ---- encode path (independent of M) ----
  const int lane = tid & 63;
  const unsigned p = blockIdx.x * 4u + (tid >> 6);   // patch id (grid exact)
  const unsigned b = p / 676u;
  const unsigned rem = p - b * 676u;
  const unsigned i = rem / 26u, j = rem - i * 26u;

  float c_enc = 0.0f, s_enc = 0.0f;
  if (lane < 9) {
    const int di = lane / 3, dj = lane - di * 3;
    const float xv = x[b * 784u + (i + di) * 28u + (j + dj)];
    const float ang = fmaf(xv, 3.14159265358979323846f, wenc[lane]) * 0.5f;
    __sincosf(ang, &s_enc, &c_enc);
  }
  float cqv[9], sqv[9];
#pragma unroll
  for (int q = 0; q < 9; ++q) { cqv[q] = __shfl(c_enc, q, 64); sqv[q] = __shfl(s_enc, q, 64); }

  const int l0 = lane & 1, l1 = (lane >> 1) & 1, l2 = (lane >> 2) & 1;
  const int l3 = (lane >> 3) & 1, l4 = (lane >> 4) & 1, l5 = (lane >> 5) & 1;

  // tau_q(bit) = (bit? s_q : c_q) * e^{i sgn(bit) wz_q/2}
  auto tau = [&](int bit, int q) -> float2 {
    const float2 z = zcs[q];
    const float m  = bit ? sqv[q] : cqv[q];
    const float zy = bit ? z.y : -z.y;
    return make_float2(m * z.x, m * zy);
  };

  // post-ring product-state factors (see header derivation)
  const int a0 = l5, a1 = l0 ^ l5;
  float2 p00 = cmul(tau(a0, 0), tau(a1, 1));
  float2 p01 = cmul(tau(a0 ^ 1, 0), tau(a1 ^ 1, 1));
  float2 p10 = cmul(tau(l1, 3), tau(l2, 4));
  float2 p11 = cmul(tau(l1 ^ 1, 3), tau(l2 ^ 1, 4));
  float2 p20 = cmul(tau(l3, 6), tau(l4, 7));
  float2 p21 = cmul(tau(l3 ^ 1, 6), tau(l4 ^ 1, 7));
  const float2 T = cmul(cmul(tau(l0 ^ l1, 2), tau(l2 ^ l3, 5)), tau(l4 ^ l5, 8));
  p20 = cmul(p20, T);
  p21 = cmul(p21, T);

  // pool1: per-lane RX applied to each 2-vector factor
  {
    const float2 x0 = rxtab[0][lane & 3];
    const float2 x1 = rxtab[1][(lane >> 2) & 3];
    const float2 x2 = rxtab[2][(lane >> 4) & 3];
    float2 nA, nB;
    nA = make_float2(x0.x * p00.x + x0.y * p01.y, x0.x * p00.y - x0.y * p01.x);
    nB = make_float2(x0.x * p01.x + x0.y * p00.y, x0.x * p01.y - x0.y * p00.x);
    p00 = nA; p01 = nB;
    nA = make_float2(x1.x * p10.x + x1.y * p11.y, x1.x * p10.y - x1.y * p11.x);
    nB = make_float2(x1.x * p11.x + x1.y * p10.y, x1.x * p11.y - x1.y * p10.x);
    p10 = nA; p11 = nB;
    nA = make_float2(x2.x * p20.x + x2.y * p21.y, x2.x * p20.y - x2.y * p21.x);
    nB = make_float2(x2.x * p21.x + x2.y * p20.y, x2.x * p21.y - x2.y * p20.x);
    p20 = nA; p21 = nB;
  }

  // expand to 8 amplitudes  u[r] = p0(r&1) * p1(r>>1&1) * p2(r>>2&1)
  float ure[8], uim[8];
  {
    const float2 q00 = cmul(p00, p10), q01v = cmul(p01, p10);
    const float2 q10 = cmul(p00, p11), q11v = cmul(p01, p11);
    const float2 qq[4] = {q00, q01v, q10, q11v};
#pragma unroll
    for (int r = 0; r < 8; ++r) {
      const float2 u = cmul(qq[r & 3], (r & 4) ? p21 : p20);
      ure[r] = u.x; uim[r] = u.y;
    }
  }

  __syncthreads();   // M ready

  // v = M u  (wave-uniform M, broadcast ds_read_b128)
  float nre[8], nim[8];
#pragma unroll
  for (int oi = 0; oi < 8; ++oi) {
    float ar = 0.0f, ai = 0.0f;
#pragma unroll
    for (int jj = 0; jj < 4; ++jj) {
      const float4 m = Msh[oi][jj];
      ar = fmaf(m.x, ure[2 * jj], ar);     ar = fmaf(-m.y, uim[2 * jj], ar);
      ai = fmaf(m.x, uim[2 * jj], ai);     ai = fmaf(m.y, ure[2 * jj], ai);
      ar = fmaf(m.z, ure[2 * jj + 1], ar); ar = fmaf(-m.w, uim[2 * jj + 1], ar);
      ai = fmaf(m.z, uim[2 * jj + 1], ai); ai = fmaf(m.w, ure[2 * jj + 1], ai);
    }
    nre[oi] = ar; nim[oi] = ai;
  }

  // <X>,<Y>,<Z> on qubit 0 (reg bit 0); ez = 2*P(even)-1
  float zr = 0.f, zi = 0.f, pe = 0.f;
#pragma unroll
  for (int r0 = 0; r0 < 8; r0 += 2) {
    const int r1 = r0 + 1;
    zr += nre[r0] * nre[r1] + nim[r0] * nim[r1];
    zi += nre[r0] * nim[r1] - nim[r0] * nre[r1];
    pe += nre[r0] * nre[r0] + nim[r0] * nim[r0];
  }
#pragma unroll
  for (int m = 1; m < 64; m <<= 1) { zr += shx(zr, m); zi += shx(zi, m); pe += shx(pe, m); }

  if (lane == 0) {
    feats[p * 3u + 0u] = 2.0f * zr;
    feats[p * 3u + 1u] = 2.0f * zi;
    feats[p * 3u + 2u] = 2.0f * pe - 1.0f;
  }
}

// out[b,c] = fc_b[c] + dot(feats[b,:], fc_w[c,:]) over 2028 elements.
__global__ __launch_bounds__(256) void fc_kernel(const float* __restrict__ feats,
                                                 const float* __restrict__ fc_w,
                                                 const float* __restrict__ fc_b,
                                                 float* __restrict__ out) {
  const int b = blockIdx.x / 10, c = blockIdx.x - b * 10;
  const float* f = feats + b * 2028;
  const float* wr = fc_w + c * 2028;
  float acc = 0.0f;
  for (int k = threadIdx.x; k < 2028; k += 256) acc += f[k] * wr[k];
#pragma unroll
  for (int m = 1; m < 64; m <<= 1) acc += __shfl_xor(acc, m, 64);
  __shared__ float sbuf[4];
  const int lane = threadIdx.x & 63, wv = threadIdx.x >> 6;
  if (lane == 0) sbuf[wv] = acc;
  __syncthreads();
  if (threadIdx.x == 0) out[b * 10 + c] = sbuf[0] + sbuf[1] + sbuf[2] + sbuf[3] + fc_b[c];
}

extern "C" void kernel_launch(void* const* d_in, const int* in_sizes, int n_in,
                              void* d_out, int out_size, void* d_ws, size_t ws_size,
                              hipStream_t stream) {
  const float* x    = (const float*)d_in[0];   // (B,1,28,28)
  const float* w    = (const float*)d_in[1];   // (42,)
  const float* fc_w = (const float*)d_in[2];   // (10, 2028)
  const float* fc_b = (const float*)d_in[3];   // (10,)
  float* out = (float*)d_out;                  // (B, 10)

  const int B = in_sizes[0] / 784;             // 8
  const int npatch = B * 676;                  // 5408; divisible by 4

  float* feats = (float*)d_ws;                 // npatch*3 floats, fully written

  qcnn_fused<<<npatch / 4, 256, 0, stream>>>(x, w, feats);
  fc_kernel<<<B * 10, 256, 0, stream>>>(feats, fc_w, fc_b, out);
}